// Round 8
// baseline (405.541 us; speedup 1.0000x reference)
//
#include <hip/hip_runtime.h>
#include <math.h>

#define NNODES 50000
#define NEDGES 800000
#define INDIM 256
#define HID 64
#define HEADS 4
#define OUTDIM 64
#define NEG_SLOPE 0.2f
#define NB ((NNODES + 1023) / 1024)   // 49 scan blocks

typedef __attribute__((ext_vector_type(4))) float f32x4;
typedef _Float16 __attribute__((ext_vector_type(8))) half8;

// ---------------- CSR build ----------------

__global__ __launch_bounds__(256) void hist_kernel(const int* __restrict__ dst,
                                                   int* __restrict__ deg) {
    int i = blockIdx.x * 256 + threadIdx.x;
    if (i < NEDGES) atomicAdd(&deg[dst[i]], 1);
}

__global__ __launch_bounds__(256) void bsum_kernel(const int* __restrict__ deg,
                                                   int* __restrict__ bsums) {
    int b = blockIdx.x, t = threadIdx.x;
    int base = b * 1024 + t * 4;
    int s = 0;
    #pragma unroll
    for (int e = 0; e < 4; ++e) { int i = base + e; if (i < NNODES) s += deg[i]; }
    #pragma unroll
    for (int o = 32; o; o >>= 1) s += __shfl_xor(s, o);
    __shared__ int ws[4];
    int lane = t & 63, wid = t >> 6;
    if (lane == 0) ws[wid] = s;
    __syncthreads();
    if (t == 0) bsums[b] = ws[0] + ws[1] + ws[2] + ws[3];
}

__global__ __launch_bounds__(256) void scan_write_kernel(const int* __restrict__ deg,
                                                         const int* __restrict__ bsums,
                                                         int* __restrict__ offs) {
    int b = blockIdx.x, t = threadIdx.x;
    int lane = t & 63, wid = t >> 6;
    int bv = (lane < b) ? bsums[lane] : 0;    // b <= NB-1 < 64
    #pragma unroll
    for (int o = 32; o; o >>= 1) bv += __shfl_xor(bv, o);  // block global offset
    int base = b * 1024 + t * 4;
    int v[4]; int tsum = 0;
    #pragma unroll
    for (int e = 0; e < 4; ++e) {
        int i = base + e;
        v[e] = (i < NNODES) ? deg[i] : 0;
        tsum += v[e];
    }
    int p = tsum;
    #pragma unroll
    for (int o = 1; o < 64; o <<= 1) { int u = __shfl_up(p, o); if (lane >= o) p += u; }
    __shared__ int ws[4];
    if (lane == 63) ws[wid] = p;
    __syncthreads();
    int woff = 0;
    for (int i = 0; i < wid; ++i) woff += ws[i];
    int run = bv + woff + p - tsum;           // exclusive prefix for this thread
    #pragma unroll
    for (int e = 0; e < 4; ++e) {
        int i = base + e;
        if (i < NNODES) { offs[i] = run; run += v[e]; }
    }
    if (b == 0 && t == 0) offs[NNODES] = NEDGES;
}

__global__ __launch_bounds__(256) void scatter_kernel(const int* __restrict__ src,
                                                      const int* __restrict__ dst,
                                                      const int* __restrict__ offs,
                                                      int* __restrict__ cursor,
                                                      int* __restrict__ ssorted) {
    int i = blockIdx.x * 256 + threadIdx.x;
    if (i < NEDGES) {
        int d = dst[i];
        int pos = offs[d] + atomicAdd(&cursor[d], 1);
        ssorted[pos] = src[i];
    }
}

// ---------------- weight transpose -> fp16 (both weights, one launch) ----

__global__ __launch_bounds__(256) void convert_wt_kernel(const float* __restrict__ W1,
                                                         _Float16* __restrict__ W1t,
                                                         const float* __restrict__ W2,
                                                         _Float16* __restrict__ W2t) {
    int idx = blockIdx.x * 256 + threadIdx.x;
    if (idx < 256 * 256) {
        int k = idx >> 8, n = idx & 255;
        W1t[n * 256 + k] = (_Float16)W1[idx];
    } else if (idx < 256 * 256 + 256 * 64) {
        int j = idx - 256 * 256;
        int k = j >> 6, n = j & 63;
        W2t[n * 256 + k] = (_Float16)W2[j];
    }
}

// ---------------- fp16 MFMA GEMM, LDS-free, 128x(BN) tile ----------------
// ELR=1 (BN=128): C node-major [M][256]; el/er NODE-MAJOR [M][4] so spmm1
//   reads all 4 heads' el with one 4B/lane gather off the same line.
// ELR=2 (BN=64): single head; per-wn partial dot + 1KB LDS combine.

template <int BN, bool AFP16, int ELR>
__global__ __launch_bounds__(256) void gemm_f16_kernel(
        const float* __restrict__ Af, const _Float16* __restrict__ Ah,
        const _Float16* __restrict__ Bt,
        _Float16* __restrict__ C,
        const float* __restrict__ al, const float* __restrict__ ar,
        float* __restrict__ el, float* __restrict__ er,
        int M, int N) {
    constexpr int K = 256;
    constexpr int NT = BN / 32;       // 16-wide n-tiles per wave
    int t = threadIdx.x;
    int lane = t & 63, w = t >> 6;
    int wm = w >> 1, wn = w & 1;
    int lr = lane & 15, quad = lane >> 4;
    int m0 = blockIdx.y * 128, n0 = blockIdx.x * BN;

    f32x4 acc[4][NT];
    #pragma unroll
    for (int i = 0; i < 4; ++i)
        #pragma unroll
        for (int j = 0; j < NT; ++j) acc[i][j] = (f32x4){0.f, 0.f, 0.f, 0.f};

    int arow[4];
    #pragma unroll
    for (int i = 0; i < 4; ++i) {
        int r = m0 + wm * 64 + i * 16 + lr;
        arow[i] = (r < M) ? r : (M - 1);
    }
    int brow[NT];
    #pragma unroll
    for (int j = 0; j < NT; ++j) brow[j] = n0 + wn * NT * 16 + j * 16 + lr;

    #pragma unroll
    for (int kk = 0; kk < K; kk += 32) {
        half8 a[4], b[NT];
        if (AFP16) {
            #pragma unroll
            for (int i = 0; i < 4; ++i)
                a[i] = *(const half8*)(Ah + (size_t)arow[i] * K + kk + quad * 8);
        } else {
            #pragma unroll
            for (int i = 0; i < 4; ++i) {
                const float* ap = Af + (size_t)arow[i] * K + kk + quad * 8;
                float4 f0 = *(const float4*)ap;
                float4 f1 = *(const float4*)(ap + 4);
                a[i][0] = (_Float16)f0.x; a[i][1] = (_Float16)f0.y;
                a[i][2] = (_Float16)f0.z; a[i][3] = (_Float16)f0.w;
                a[i][4] = (_Float16)f1.x; a[i][5] = (_Float16)f1.y;
                a[i][6] = (_Float16)f1.z; a[i][7] = (_Float16)f1.w;
            }
        }
        #pragma unroll
        for (int j = 0; j < NT; ++j)
            b[j] = *(const half8*)(Bt + (size_t)brow[j] * K + kk + quad * 8);
        #pragma unroll
        for (int i = 0; i < 4; ++i)
            #pragma unroll
            for (int j = 0; j < NT; ++j)
                acc[i][j] = __builtin_amdgcn_mfma_f32_16x16x32_f16(a[i], b[j], acc[i][j], 0, 0, 0);
    }
    #pragma unroll
    for (int i = 0; i < 4; ++i) {
        #pragma unroll
        for (int r = 0; r < 4; ++r) {
            int row = m0 + wm * 64 + i * 16 + quad * 4 + r;
            if (row < M) {
                #pragma unroll
                for (int j = 0; j < NT; ++j)
                    C[(size_t)row * N + n0 + wn * NT * 16 + j * 16 + lr] =
                        (_Float16)acc[i][j][r];
            }
        }
    }
    if constexpr (ELR == 1) {
        int h = n0 / 64 + wn;
        float alh[NT], arh[NT];
        #pragma unroll
        for (int j = 0; j < NT; ++j) {
            alh[j] = al[h * 64 + j * 16 + lr];
            arh[j] = ar[h * 64 + j * 16 + lr];
        }
        #pragma unroll
        for (int i = 0; i < 4; ++i) {
            #pragma unroll
            for (int r = 0; r < 4; ++r) {
                float pel = 0.f, per = 0.f;
                #pragma unroll
                for (int j = 0; j < NT; ++j) {
                    pel = fmaf(acc[i][j][r], alh[j], pel);
                    per = fmaf(acc[i][j][r], arh[j], per);
                }
                #pragma unroll
                for (int o = 1; o < 16; o <<= 1) {
                    pel += __shfl_xor(pel, o);
                    per += __shfl_xor(per, o);
                }
                if (lr == 0) {
                    int row = m0 + wm * 64 + i * 16 + quad * 4 + r;
                    if (row < M) {
                        el[(size_t)row * 4 + h] = pel;   // node-major [M][4]
                        er[(size_t)row * 4 + h] = per;
                    }
                }
            }
        }
    }
    if constexpr (ELR == 2) {
        __shared__ float elbuf[128], erbuf[128];
        float alv[NT], arv[NT];
        #pragma unroll
        for (int j = 0; j < NT; ++j) {
            alv[j] = al[wn * NT * 16 + j * 16 + lr];
            arv[j] = ar[wn * NT * 16 + j * 16 + lr];
        }
        float pel_s[4][4], per_s[4][4];
        #pragma unroll
        for (int i = 0; i < 4; ++i) {
            #pragma unroll
            for (int r = 0; r < 4; ++r) {
                float pel = 0.f, per = 0.f;
                #pragma unroll
                for (int j = 0; j < NT; ++j) {
                    pel = fmaf(acc[i][j][r], alv[j], pel);
                    per = fmaf(acc[i][j][r], arv[j], per);
                }
                #pragma unroll
                for (int o = 1; o < 16; o <<= 1) {
                    pel += __shfl_xor(pel, o);
                    per += __shfl_xor(per, o);
                }
                pel_s[i][r] = pel; per_s[i][r] = per;
            }
        }
        if (wn == 1 && lr == 0) {
            #pragma unroll
            for (int i = 0; i < 4; ++i)
                #pragma unroll
                for (int r = 0; r < 4; ++r) {
                    int rl = wm * 64 + i * 16 + quad * 4 + r;
                    elbuf[rl] = pel_s[i][r];
                    erbuf[rl] = per_s[i][r];
                }
        }
        __syncthreads();
        if (wn == 0 && lr == 0) {
            #pragma unroll
            for (int i = 0; i < 4; ++i)
                #pragma unroll
                for (int r = 0; r < 4; ++r) {
                    int rl = wm * 64 + i * 16 + quad * 4 + r;
                    int row = m0 + rl;
                    if (row < M) {
                        el[row] = pel_s[i][r] + elbuf[rl];
                        er[row] = per_s[i][r] + erbuf[rl];
                    }
                }
        }
    }
}

// ---------------- fused softmax + weighted aggregation (layer 1) ----------
// R19: single-pass 32 edges. R18 PMC (VALU 34%, occ 43%, nothing saturated,
// ~17k-cy wave lifetime by Little's law) -> loaded-latency regime. With
// Poisson(16) degrees, the 16-edge pass forced a second serial loaded-
// latency round trip for ~43% of waves. Now 16 slots x 2 edges = 32 edges
// per pass (P(deg<=32) ~ 0.9998): 48 VMEM loads issued back-to-back per
// wave, one serial round trip for virtually all nodes. n forced to SGPR
// (readfirstlane) so the offs head-of-chain loads go scalar.

__global__ __launch_bounds__(256) void spmm1_kernel(const _Float16* __restrict__ feat,  // [N][256]
                                                    const float* __restrict__ el,  // [N][4]
                                                    const float* __restrict__ er,  // [N][4]
                                                    const int* __restrict__ offs,
                                                    const int* __restrict__ ssorted,
                                                    _Float16* __restrict__ h1) {
    int n = blockIdx.x * 4 + (threadIdx.x >> 6);   // wave = node, all 4 heads
    n = __builtin_amdgcn_readfirstlane(n);
    if (n >= NNODES) return;
    int l = threadIdx.x & 63;
    int p2 = l >> 5;              // edge-pair slot (2 edges per VMEM)
    int q  = l & 31;              // 32 lanes cover 512B = 4 heads x 64 dims
    int h  = q >> 3;              // this lane's head
    int start = offs[n], end = offs[n + 1];
    float ern = er[(size_t)n * 4 + h];
    const half8* f8 = (const half8*)feat;   // node stride 32 half8
    float acc[8];
    #pragma unroll
    for (int i = 0; i < 8; ++i) acc[i] = 0.f;
    float ws = 0.f;
    for (int base = start; base < end; base += 32) {   // 1 pass for deg<=32 (99.98%)
        #pragma unroll
        for (int js = 0; js < 16; ++js) {
            int idx = base + js * 2 + p2;
            bool vld = idx < end;
            int ic = vld ? idx : start;
            int sj = ssorted[ic];                      // 2 addrs per wave-instr
            float ev = el[(size_t)sj * 4 + h] + ern;   // all heads, one line
            ev = ev > 0.f ? ev : NEG_SLOPE * ev;
            float w = vld ? __expf(ev) : 0.f;          // no max-sub (safe: |e|<~8)
            half8 fv = f8[(size_t)sj * 32 + q];        // 2x512B contiguous bursts
            ws += w;
            #pragma unroll
            for (int i = 0; i < 8; ++i) acc[i] = fmaf(w, (float)fv[i], acc[i]);
        }
    }
    // fold the two edge-pair halves
    ws += __shfl_xor(ws, 32);
    #pragma unroll
    for (int i = 0; i < 8; ++i) acc[i] += __shfl_xor(acc[i], 32);
    if (l < 32) {
        float inv = ws > 0.f ? 1.f / ws : 0.f;
        half8 hv;
        #pragma unroll
        for (int i = 0; i < 8; ++i) {
            float v = acc[i] * inv;
            v = v > 0.f ? v : __expf(v) - 1.f;   // ELU
            hv[i] = (_Float16)v;
        }
        *(half8*)&h1[(size_t)n * 256 + q * 8] = hv;    // 512B/node contiguous
    }
}

// ---------------- fused softmax + weighted aggregation (layer 2) ----------
// Single head: 32 edges/pass already. readfirstlane added.

__global__ __launch_bounds__(256) void spmm2_kernel(const _Float16* __restrict__ feat,
                                                    const float* __restrict__ el,
                                                    const float* __restrict__ er,
                                                    const int* __restrict__ offs,
                                                    const int* __restrict__ ssorted,
                                                    float* __restrict__ out) {
    int n = blockIdx.x * 4 + (threadIdx.x >> 6);
    n = __builtin_amdgcn_readfirstlane(n);
    if (n >= NNODES) return;
    int l = threadIdx.x & 63;
    int e8 = l >> 3, li = l & 7;
    int start = offs[n], end = offs[n + 1];
    float ern = er[n];
    const half8* f8 = (const half8*)feat;   // node stride 8 half8s
    float acc[8];
    #pragma unroll
    for (int i = 0; i < 8; ++i) acc[i] = 0.f;
    float ws = 0.f;
    for (int base = start; base < end; base += 32) {
        #pragma unroll
        for (int js = 0; js < 4; ++js) {
            int idx = base + js * 8 + e8;
            bool vld = idx < end;
            int ic = vld ? idx : start;
            int sj = ssorted[ic];
            float ev = el[sj] + ern;
            ev = ev > 0.f ? ev : NEG_SLOPE * ev;
            float w = vld ? __expf(ev) : 0.f;
            half8 fv = f8[(size_t)sj * 8 + li];
            ws += w;
            #pragma unroll
            for (int i = 0; i < 8; ++i) acc[i] = fmaf(w, (float)fv[i], acc[i]);
        }
    }
    #pragma unroll
    for (int o = 8; o < 64; o <<= 1) {
        ws += __shfl_xor(ws, o);
        #pragma unroll
        for (int i = 0; i < 8; ++i) acc[i] += __shfl_xor(acc[i], o);
    }
    if (e8 == 0) {
        float inv = ws > 0.f ? 1.f / ws : 0.f;
        float4 o0, o1;
        o0.x = acc[0] * inv; o0.y = acc[1] * inv;
        o0.z = acc[2] * inv; o0.w = acc[3] * inv;
        o1.x = acc[4] * inv; o1.y = acc[5] * inv;
        o1.z = acc[6] * inv; o1.w = acc[7] * inv;
        float4* op = (float4*)(out + (size_t)n * 64 + li * 8);
        op[0] = o0; op[1] = o1;
    }
}

// ---------------- launch ----------------

extern "C" void kernel_launch(void* const* d_in, const int* in_sizes, int n_in,
                              void* d_out, int out_size, void* d_ws, size_t ws_size,
                              hipStream_t stream) {
    const float* x   = (const float*)d_in[0];
    const int*   src = (const int*)d_in[1];
    const int*   dst = (const int*)d_in[2];
    const float* W1  = (const float*)d_in[3];
    const float* al1 = (const float*)d_in[4];
    const float* ar1 = (const float*)d_in[5];
    const float* W2  = (const float*)d_in[6];
    const float* al2 = (const float*)d_in[7];
    const float* ar2 = (const float*)d_in[8];
    float* out = (float*)d_out;

    char* ws = (char*)d_ws;
    size_t off = 0;
    auto alloc = [&](size_t bytes) -> void* {
        void* p = ws + off;
        off += (bytes + 255) & ~(size_t)255;
        return p;
    };
    _Float16* feat1 = (_Float16*)alloc((size_t)NNODES * 256 * 2);   // node-major [N][256]
    _Float16* h1    = (_Float16*)alloc((size_t)NNODES * 256 * 2);   // node-major [N][256]
    _Float16* W1t   = (_Float16*)alloc((size_t)256 * 256 * 2);
    _Float16* W2t   = (_Float16*)alloc((size_t)64 * 256 * 2);
    float* el1    = (float*)alloc((size_t)NNODES * 4 * 4);          // node-major [N][4]
    float* er1    = (float*)alloc((size_t)NNODES * 4 * 4);
    float* el2    = (float*)alloc((size_t)NNODES * 4);
    float* er2    = (float*)alloc((size_t)NNODES * 4);
    int* deg      = (int*)alloc((size_t)NNODES * 4);
    int* cursor   = (int*)alloc((size_t)NNODES * 4);
    int* offs     = (int*)alloc((size_t)(NNODES + 1) * 4);
    int* bsums    = (int*)alloc((size_t)NB * 4);
    int* ssorted  = (int*)alloc((size_t)NEDGES * 4);
    _Float16* feat2 = feat1;   // feat1 dead after spmm1; reuse for layer 2

    // --- CSR build ---
    hipMemsetAsync(deg, 0, (size_t)NNODES * 4, stream);
    hipMemsetAsync(cursor, 0, (size_t)NNODES * 4, stream);
    hist_kernel<<<(NEDGES + 255) / 256, 256, 0, stream>>>(dst, deg);
    bsum_kernel<<<NB, 256, 0, stream>>>(deg, bsums);
    scan_write_kernel<<<NB, 256, 0, stream>>>(deg, bsums, offs);
    scatter_kernel<<<(NEDGES + 255) / 256, 256, 0, stream>>>(src, dst, offs, cursor, ssorted);

    // --- weight conversions (single launch) ---
    convert_wt_kernel<<<(256 * 256 + 256 * 64 + 255) / 256, 256, 0, stream>>>(
        W1, W1t, W2, W2t);

    // --- Layer 1: GEMM (node-major feat + el/er); all-heads fused SpMM ---
    gemm_f16_kernel<128, false, 1><<<dim3(256 / 128, (NNODES + 127) / 128), 256, 0, stream>>>(
        x, nullptr, W1t, feat1, al1, ar1, el1, er1, NNODES, 256);
    spmm1_kernel<<<(NNODES + 3) / 4, 256, 0, stream>>>(
        feat1, el1, er1, offs, ssorted, h1);

    // --- Layer 2: fp16 GEMM + fused single-head el/er; fused-softmax SpMM ---
    gemm_f16_kernel<64, true, 2><<<dim3(64 / 64, (NNODES + 127) / 128), 256, 0, stream>>>(
        nullptr, h1, W2t, feat2, al2, ar2, el2, er2, NNODES, 64);
    spmm2_kernel<<<(NNODES + 3) / 4, 256, 0, stream>>>(
        feat2, el2, er2, offs, ssorted, out);
}

// Round 9
// 360.166 us; speedup vs baseline: 1.1260x; 1.1260x over previous
//
#include <hip/hip_runtime.h>
#include <math.h>

#define NNODES 50000
#define NEDGES 800000
#define INDIM 256
#define HID 64
#define HEADS 4
#define OUTDIM 64
#define NEG_SLOPE 0.2f
#define NB ((NNODES + 1023) / 1024)   // 49 scan blocks

typedef __attribute__((ext_vector_type(4))) float f32x4;
typedef _Float16 __attribute__((ext_vector_type(8))) half8;

// ---------------- CSR build ----------------

__global__ __launch_bounds__(256) void hist_kernel(const int* __restrict__ dst,
                                                   int* __restrict__ deg) {
    int i = blockIdx.x * 256 + threadIdx.x;
    if (i < NEDGES) atomicAdd(&deg[dst[i]], 1);
}

__global__ __launch_bounds__(256) void bsum_kernel(const int* __restrict__ deg,
                                                   int* __restrict__ bsums) {
    int b = blockIdx.x, t = threadIdx.x;
    int base = b * 1024 + t * 4;
    int s = 0;
    #pragma unroll
    for (int e = 0; e < 4; ++e) { int i = base + e; if (i < NNODES) s += deg[i]; }
    #pragma unroll
    for (int o = 32; o; o >>= 1) s += __shfl_xor(s, o);
    __shared__ int ws[4];
    int lane = t & 63, wid = t >> 6;
    if (lane == 0) ws[wid] = s;
    __syncthreads();
    if (t == 0) bsums[b] = ws[0] + ws[1] + ws[2] + ws[3];
}

__global__ __launch_bounds__(256) void scan_write_kernel(const int* __restrict__ deg,
                                                         const int* __restrict__ bsums,
                                                         int* __restrict__ offs) {
    int b = blockIdx.x, t = threadIdx.x;
    int lane = t & 63, wid = t >> 6;
    int bv = (lane < b) ? bsums[lane] : 0;    // b <= NB-1 < 64
    #pragma unroll
    for (int o = 32; o; o >>= 1) bv += __shfl_xor(bv, o);  // block global offset
    int base = b * 1024 + t * 4;
    int v[4]; int tsum = 0;
    #pragma unroll
    for (int e = 0; e < 4; ++e) {
        int i = base + e;
        v[e] = (i < NNODES) ? deg[i] : 0;
        tsum += v[e];
    }
    int p = tsum;
    #pragma unroll
    for (int o = 1; o < 64; o <<= 1) { int u = __shfl_up(p, o); if (lane >= o) p += u; }
    __shared__ int ws[4];
    if (lane == 63) ws[wid] = p;
    __syncthreads();
    int woff = 0;
    for (int i = 0; i < wid; ++i) woff += ws[i];
    int run = bv + woff + p - tsum;           // exclusive prefix for this thread
    #pragma unroll
    for (int e = 0; e < 4; ++e) {
        int i = base + e;
        if (i < NNODES) { offs[i] = run; run += v[e]; }
    }
    if (b == 0 && t == 0) offs[NNODES] = NEDGES;
}

__global__ __launch_bounds__(256) void scatter_kernel(const int* __restrict__ src,
                                                      const int* __restrict__ dst,
                                                      const int* __restrict__ offs,
                                                      int* __restrict__ cursor,
                                                      int* __restrict__ ssorted) {
    int i = blockIdx.x * 256 + threadIdx.x;
    if (i < NEDGES) {
        int d = dst[i];
        int pos = offs[d] + atomicAdd(&cursor[d], 1);
        ssorted[pos] = src[i];
    }
}

// ---------------- weight transpose -> fp16 (both weights, one launch) ----

__global__ __launch_bounds__(256) void convert_wt_kernel(const float* __restrict__ W1,
                                                         _Float16* __restrict__ W1t,
                                                         const float* __restrict__ W2,
                                                         _Float16* __restrict__ W2t) {
    int idx = blockIdx.x * 256 + threadIdx.x;
    if (idx < 256 * 256) {
        int k = idx >> 8, n = idx & 255;
        W1t[n * 256 + k] = (_Float16)W1[idx];
    } else if (idx < 256 * 256 + 256 * 64) {
        int j = idx - 256 * 256;
        int k = j >> 6, n = j & 63;
        W2t[n * 256 + k] = (_Float16)W2[j];
    }
}

// ---------------- fp16 MFMA GEMM, LDS-free, 128x(BN) tile ----------------
// ELR=1 (BN=128): C node-major [M][256]; el/er NODE-MAJOR [M][4] so spmm1
//   reads all 4 heads' el with one 4B/lane gather off the same line.
// ELR=2 (BN=64): single head; per-wn partial dot + 1KB LDS combine.

template <int BN, bool AFP16, int ELR>
__global__ __launch_bounds__(256) void gemm_f16_kernel(
        const float* __restrict__ Af, const _Float16* __restrict__ Ah,
        const _Float16* __restrict__ Bt,
        _Float16* __restrict__ C,
        const float* __restrict__ al, const float* __restrict__ ar,
        float* __restrict__ el, float* __restrict__ er,
        int M, int N) {
    constexpr int K = 256;
    constexpr int NT = BN / 32;       // 16-wide n-tiles per wave
    int t = threadIdx.x;
    int lane = t & 63, w = t >> 6;
    int wm = w >> 1, wn = w & 1;
    int lr = lane & 15, quad = lane >> 4;
    int m0 = blockIdx.y * 128, n0 = blockIdx.x * BN;

    f32x4 acc[4][NT];
    #pragma unroll
    for (int i = 0; i < 4; ++i)
        #pragma unroll
        for (int j = 0; j < NT; ++j) acc[i][j] = (f32x4){0.f, 0.f, 0.f, 0.f};

    int arow[4];
    #pragma unroll
    for (int i = 0; i < 4; ++i) {
        int r = m0 + wm * 64 + i * 16 + lr;
        arow[i] = (r < M) ? r : (M - 1);
    }
    int brow[NT];
    #pragma unroll
    for (int j = 0; j < NT; ++j) brow[j] = n0 + wn * NT * 16 + j * 16 + lr;

    #pragma unroll
    for (int kk = 0; kk < K; kk += 32) {
        half8 a[4], b[NT];
        if (AFP16) {
            #pragma unroll
            for (int i = 0; i < 4; ++i)
                a[i] = *(const half8*)(Ah + (size_t)arow[i] * K + kk + quad * 8);
        } else {
            #pragma unroll
            for (int i = 0; i < 4; ++i) {
                const float* ap = Af + (size_t)arow[i] * K + kk + quad * 8;
                float4 f0 = *(const float4*)ap;
                float4 f1 = *(const float4*)(ap + 4);
                a[i][0] = (_Float16)f0.x; a[i][1] = (_Float16)f0.y;
                a[i][2] = (_Float16)f0.z; a[i][3] = (_Float16)f0.w;
                a[i][4] = (_Float16)f1.x; a[i][5] = (_Float16)f1.y;
                a[i][6] = (_Float16)f1.z; a[i][7] = (_Float16)f1.w;
            }
        }
        #pragma unroll
        for (int j = 0; j < NT; ++j)
            b[j] = *(const half8*)(Bt + (size_t)brow[j] * K + kk + quad * 8);
        #pragma unroll
        for (int i = 0; i < 4; ++i)
            #pragma unroll
            for (int j = 0; j < NT; ++j)
                acc[i][j] = __builtin_amdgcn_mfma_f32_16x16x32_f16(a[i], b[j], acc[i][j], 0, 0, 0);
    }
    #pragma unroll
    for (int i = 0; i < 4; ++i) {
        #pragma unroll
        for (int r = 0; r < 4; ++r) {
            int row = m0 + wm * 64 + i * 16 + quad * 4 + r;
            if (row < M) {
                #pragma unroll
                for (int j = 0; j < NT; ++j)
                    C[(size_t)row * N + n0 + wn * NT * 16 + j * 16 + lr] =
                        (_Float16)acc[i][j][r];
            }
        }
    }
    if constexpr (ELR == 1) {
        int h = n0 / 64 + wn;
        float alh[NT], arh[NT];
        #pragma unroll
        for (int j = 0; j < NT; ++j) {
            alh[j] = al[h * 64 + j * 16 + lr];
            arh[j] = ar[h * 64 + j * 16 + lr];
        }
        #pragma unroll
        for (int i = 0; i < 4; ++i) {
            #pragma unroll
            for (int r = 0; r < 4; ++r) {
                float pel = 0.f, per = 0.f;
                #pragma unroll
                for (int j = 0; j < NT; ++j) {
                    pel = fmaf(acc[i][j][r], alh[j], pel);
                    per = fmaf(acc[i][j][r], arh[j], per);
                }
                #pragma unroll
                for (int o = 1; o < 16; o <<= 1) {
                    pel += __shfl_xor(pel, o);
                    per += __shfl_xor(per, o);
                }
                if (lr == 0) {
                    int row = m0 + wm * 64 + i * 16 + quad * 4 + r;
                    if (row < M) {
                        el[(size_t)row * 4 + h] = pel;   // node-major [M][4]
                        er[(size_t)row * 4 + h] = per;
                    }
                }
            }
        }
    }
    if constexpr (ELR == 2) {
        __shared__ float elbuf[128], erbuf[128];
        float alv[NT], arv[NT];
        #pragma unroll
        for (int j = 0; j < NT; ++j) {
            alv[j] = al[wn * NT * 16 + j * 16 + lr];
            arv[j] = ar[wn * NT * 16 + j * 16 + lr];
        }
        float pel_s[4][4], per_s[4][4];
        #pragma unroll
        for (int i = 0; i < 4; ++i) {
            #pragma unroll
            for (int r = 0; r < 4; ++r) {
                float pel = 0.f, per = 0.f;
                #pragma unroll
                for (int j = 0; j < NT; ++j) {
                    pel = fmaf(acc[i][j][r], alv[j], pel);
                    per = fmaf(acc[i][j][r], arv[j], per);
                }
                #pragma unroll
                for (int o = 1; o < 16; o <<= 1) {
                    pel += __shfl_xor(pel, o);
                    per += __shfl_xor(per, o);
                }
                pel_s[i][r] = pel; per_s[i][r] = per;
            }
        }
        if (wn == 1 && lr == 0) {
            #pragma unroll
            for (int i = 0; i < 4; ++i)
                #pragma unroll
                for (int r = 0; r < 4; ++r) {
                    int rl = wm * 64 + i * 16 + quad * 4 + r;
                    elbuf[rl] = pel_s[i][r];
                    erbuf[rl] = per_s[i][r];
                }
        }
        __syncthreads();
        if (wn == 0 && lr == 0) {
            #pragma unroll
            for (int i = 0; i < 4; ++i)
                #pragma unroll
                for (int r = 0; r < 4; ++r) {
                    int rl = wm * 64 + i * 16 + quad * 4 + r;
                    int row = m0 + rl;
                    if (row < M) {
                        el[row] = pel_s[i][r] + elbuf[rl];
                        er[row] = per_s[i][r] + erbuf[rl];
                    }
                }
        }
    }
}

// ---------------- fused softmax + weighted aggregation (layer 1) ----------
// R20: R18 structure (102us, best) + wave-uniform slot guards. R19 lesson:
// masked slots still ISSUE their loads (clamped addr) -> doubled requests
// in a queue-limited regime. base/end/js are wave-uniform, so
// `if (base + js*2 < end)` is a scalar branch that skips dead slots'
// VMEM issue entirely (~25-30% fewer requests at Poisson(16) degrees).
// Only the boundary slot keeps per-lane masking.

__global__ __launch_bounds__(256) void spmm1_kernel(const _Float16* __restrict__ feat,  // [N][256]
                                                    const float* __restrict__ el,  // [N][4]
                                                    const float* __restrict__ er,  // [N][4]
                                                    const int* __restrict__ offs,
                                                    const int* __restrict__ ssorted,
                                                    _Float16* __restrict__ h1) {
    int n = blockIdx.x * 4 + (threadIdx.x >> 6);   // wave = node, all 4 heads
    if (n >= NNODES) return;
    int l = threadIdx.x & 63;
    int p2 = l >> 5;              // edge-pair slot (2 edges per VMEM)
    int q  = l & 31;              // 32 lanes cover 512B = 4 heads x 64 dims
    int h  = q >> 3;              // this lane's head
    int start = offs[n], end = offs[n + 1];
    float ern = er[(size_t)n * 4 + h];
    const half8* f8 = (const half8*)feat;   // node stride 32 half8
    float acc[8];
    #pragma unroll
    for (int i = 0; i < 8; ++i) acc[i] = 0.f;
    float ws = 0.f;
    for (int base = start; base < end; base += 16) {
        #pragma unroll
        for (int js = 0; js < 8; ++js) {
            if (base + js * 2 < end) {                 // wave-uniform: skip dead slots
                int idx = base + js * 2 + p2;
                bool vld = idx < end;
                int ic = vld ? idx : start;
                int sj = ssorted[ic];                  // 2 addrs per wave-instr
                float ev = el[(size_t)sj * 4 + h] + ern;   // all heads, one line
                ev = ev > 0.f ? ev : NEG_SLOPE * ev;
                float w = vld ? __expf(ev) : 0.f;      // no max-sub (safe: |e|<~8)
                half8 fv = f8[(size_t)sj * 32 + q];    // 2x512B contiguous bursts
                ws += w;
                #pragma unroll
                for (int i = 0; i < 8; ++i) acc[i] = fmaf(w, (float)fv[i], acc[i]);
            }
        }
    }
    // fold the two edge-pair halves
    ws += __shfl_xor(ws, 32);
    #pragma unroll
    for (int i = 0; i < 8; ++i) acc[i] += __shfl_xor(acc[i], 32);
    if (l < 32) {
        float inv = ws > 0.f ? 1.f / ws : 0.f;
        half8 hv;
        #pragma unroll
        for (int i = 0; i < 8; ++i) {
            float v = acc[i] * inv;
            v = v > 0.f ? v : __expf(v) - 1.f;   // ELU
            hv[i] = (_Float16)v;
        }
        *(half8*)&h1[(size_t)n * 256 + q * 8] = hv;    // 512B/node contiguous
    }
}

// ---------------- fused softmax + weighted aggregation (layer 2) ----------
// Single head, 64 dims, fp32 out. Same wave-uniform slot guards.

__global__ __launch_bounds__(256) void spmm2_kernel(const _Float16* __restrict__ feat,
                                                    const float* __restrict__ el,
                                                    const float* __restrict__ er,
                                                    const int* __restrict__ offs,
                                                    const int* __restrict__ ssorted,
                                                    float* __restrict__ out) {
    int n = blockIdx.x * 4 + (threadIdx.x >> 6);
    if (n >= NNODES) return;
    int l = threadIdx.x & 63;
    int e8 = l >> 3, li = l & 7;
    int start = offs[n], end = offs[n + 1];
    float ern = er[n];
    const half8* f8 = (const half8*)feat;   // node stride 8 half8s
    float acc[8];
    #pragma unroll
    for (int i = 0; i < 8; ++i) acc[i] = 0.f;
    float ws = 0.f;
    for (int base = start; base < end; base += 32) {
        #pragma unroll
        for (int js = 0; js < 4; ++js) {
            if (base + js * 8 < end) {                 // wave-uniform: skip dead slots
                int idx = base + js * 8 + e8;
                bool vld = idx < end;
                int ic = vld ? idx : start;
                int sj = ssorted[ic];
                float ev = el[sj] + ern;
                ev = ev > 0.f ? ev : NEG_SLOPE * ev;
                float w = vld ? __expf(ev) : 0.f;
                half8 fv = f8[(size_t)sj * 8 + li];
                ws += w;
                #pragma unroll
                for (int i = 0; i < 8; ++i) acc[i] = fmaf(w, (float)fv[i], acc[i]);
            }
        }
    }
    #pragma unroll
    for (int o = 8; o < 64; o <<= 1) {
        ws += __shfl_xor(ws, o);
        #pragma unroll
        for (int i = 0; i < 8; ++i) acc[i] += __shfl_xor(acc[i], o);
    }
    if (e8 == 0) {
        float inv = ws > 0.f ? 1.f / ws : 0.f;
        float4 o0, o1;
        o0.x = acc[0] * inv; o0.y = acc[1] * inv;
        o0.z = acc[2] * inv; o0.w = acc[3] * inv;
        o1.x = acc[4] * inv; o1.y = acc[5] * inv;
        o1.z = acc[6] * inv; o1.w = acc[7] * inv;
        float4* op = (float4*)(out + (size_t)n * 64 + li * 8);
        op[0] = o0; op[1] = o1;
    }
}

// ---------------- launch ----------------

extern "C" void kernel_launch(void* const* d_in, const int* in_sizes, int n_in,
                              void* d_out, int out_size, void* d_ws, size_t ws_size,
                              hipStream_t stream) {
    const float* x   = (const float*)d_in[0];
    const int*   src = (const int*)d_in[1];
    const int*   dst = (const int*)d_in[2];
    const float* W1  = (const float*)d_in[3];
    const float* al1 = (const float*)d_in[4];
    const float* ar1 = (const float*)d_in[5];
    const float* W2  = (const float*)d_in[6];
    const float* al2 = (const float*)d_in[7];
    const float* ar2 = (const float*)d_in[8];
    float* out = (float*)d_out;

    char* ws = (char*)d_ws;
    size_t off = 0;
    auto alloc = [&](size_t bytes) -> void* {
        void* p = ws + off;
        off += (bytes + 255) & ~(size_t)255;
        return p;
    };
    _Float16* feat1 = (_Float16*)alloc((size_t)NNODES * 256 * 2);   // node-major [N][256]
    _Float16* h1    = (_Float16*)alloc((size_t)NNODES * 256 * 2);   // node-major [N][256]
    _Float16* W1t   = (_Float16*)alloc((size_t)256 * 256 * 2);
    _Float16* W2t   = (_Float16*)alloc((size_t)64 * 256 * 2);
    float* el1    = (float*)alloc((size_t)NNODES * 4 * 4);          // node-major [N][4]
    float* er1    = (float*)alloc((size_t)NNODES * 4 * 4);
    float* el2    = (float*)alloc((size_t)NNODES * 4);
    float* er2    = (float*)alloc((size_t)NNODES * 4);
    int* deg      = (int*)alloc((size_t)NNODES * 4);
    int* cursor   = (int*)alloc((size_t)NNODES * 4);
    int* offs     = (int*)alloc((size_t)(NNODES + 1) * 4);
    int* bsums    = (int*)alloc((size_t)NB * 4);
    int* ssorted  = (int*)alloc((size_t)NEDGES * 4);
    _Float16* feat2 = feat1;   // feat1 dead after spmm1; reuse for layer 2

    // --- CSR build ---
    hipMemsetAsync(deg, 0, (size_t)NNODES * 4, stream);
    hipMemsetAsync(cursor, 0, (size_t)NNODES * 4, stream);
    hist_kernel<<<(NEDGES + 255) / 256, 256, 0, stream>>>(dst, deg);
    bsum_kernel<<<NB, 256, 0, stream>>>(deg, bsums);
    scan_write_kernel<<<NB, 256, 0, stream>>>(deg, bsums, offs);
    scatter_kernel<<<(NEDGES + 255) / 256, 256, 0, stream>>>(src, dst, offs, cursor, ssorted);

    // --- weight conversions (single launch) ---
    convert_wt_kernel<<<(256 * 256 + 256 * 64 + 255) / 256, 256, 0, stream>>>(
        W1, W1t, W2, W2t);

    // --- Layer 1: GEMM (node-major feat + el/er); all-heads fused SpMM ---
    gemm_f16_kernel<128, false, 1><<<dim3(256 / 128, (NNODES + 127) / 128), 256, 0, stream>>>(
        x, nullptr, W1t, feat1, al1, ar1, el1, er1, NNODES, 256);
    spmm1_kernel<<<(NNODES + 3) / 4, 256, 0, stream>>>(
        feat1, el1, er1, offs, ssorted, h1);

    // --- Layer 2: fp16 GEMM + fused single-head el/er; fused-softmax SpMM ---
    gemm_f16_kernel<64, true, 2><<<dim3(64 / 64, (NNODES + 127) / 128), 256, 0, stream>>>(
        nullptr, h1, W2t, feat2, al2, ar2, el2, er2, NNODES, 64);
    spmm2_kernel<<<(NNODES + 3) / 4, 256, 0, stream>>>(
        feat2, el2, er2, offs, ssorted, out);
}